// Round 1
// 330.468 us; speedup vs baseline: 1.0772x; 1.0772x over previous
//
#include <hip/hip_runtime.h>
#include <hip/hip_bf16.h>

#define B_   8
#define S_   2048
#define DM   1024
#define DH   128
#define BS_  16384
#define SCALE_  0.08838834764831845f
#define SCALE2_ 0.12751744f   // SCALE * log2(e)

typedef unsigned short u16;
typedef unsigned int   u32;
typedef _Float16 half8 __attribute__((ext_vector_type(8)));
typedef float    f32x4 __attribute__((ext_vector_type(4)));
typedef u32      u32x4 __attribute__((ext_vector_type(4)));

union H8 { u32x4 v; u32 u[4]; half8 h; };

__device__ __forceinline__ float bf2f(u16 u) {
    union { u32 i; float f; } w; w.i = ((u32)u) << 16; return w.f;
}
__device__ __forceinline__ void unpack8(uint4 v, float* f) {
    f[0] = bf2f(v.x & 0xffff); f[1] = bf2f(v.x >> 16);
    f[2] = bf2f(v.y & 0xffff); f[3] = bf2f(v.y >> 16);
    f[4] = bf2f(v.z & 0xffff); f[5] = bf2f(v.z >> 16);
    f[6] = bf2f(v.w & 0xffff); f[7] = bf2f(v.w >> 16);
}
__device__ __forceinline__ float ldE(const void* b, size_t i, int isbf16) {
    return isbf16 ? bf2f(((const u16*)b)[i]) : ((const float*)b)[i];
}
__device__ __forceinline__ void ld8(const void* b, size_t i, int isbf16, float* f) {
    if (isbf16) {
        unpack8(*(const uint4*)((const u16*)b + i), f);
    } else {
        float4 a = *(const float4*)((const float*)b + i);
        float4 c = *(const float4*)((const float*)b + i + 4);
        f[0] = a.x; f[1] = a.y; f[2] = a.z; f[3] = a.w;
        f[4] = c.x; f[5] = c.y; f[6] = c.z; f[7] = c.w;
    }
}
// fp32 -> packed (f16 hi << 16) | f16 lo  (2-term split, ~22 mantissa bits)
__device__ __forceinline__ u32 f2pk(float v) {
    _Float16 h = (_Float16)v;
    _Float16 l = (_Float16)(v - (float)h);
    union { _Float16 f; u16 u; } a, b; a.f = h; b.f = l;
    return ((u32)a.u << 16) | (u32)b.u;
}
// 8 floats -> pair-packed hi/lo frag u32x4
__device__ __forceinline__ void split8(const float* f, u32x4& hi, u32x4& lo) {
    u32 H[8], L[8];
#pragma unroll
    for (int j = 0; j < 8; ++j) {
        _Float16 h = (_Float16)f[j];
        _Float16 l = (_Float16)(f[j] - (float)h);
        union { _Float16 x; u16 u; } a, b; a.x = h; b.x = l;
        H[j] = a.u; L[j] = b.u;
    }
    hi = (u32x4){H[0] | (H[1] << 16), H[2] | (H[3] << 16), H[4] | (H[5] << 16), H[6] | (H[7] << 16)};
    lo = (u32x4){L[0] | (L[1] << 16), L[2] | (L[3] << 16), L[4] | (L[5] << 16), L[6] | (L[7] << 16)};
}
__device__ __forceinline__ u32 permHI(u32 eB, u32 eA) { return __builtin_amdgcn_perm(eB, eA, 0x07060302u); }
__device__ __forceinline__ u32 permLO(u32 eB, u32 eA) { return __builtin_amdgcn_perm(eB, eA, 0x05040100u); }

// ---------------- init: dtype detect + active mask + round counters ----------------
__global__ void init_kernel(const void* x, int* flag, int* active, int* counts) {
    int i = blockIdx.x * 256 + threadIdx.x;
    if (i < BS_) active[i] = 1;
    if (i < 4) counts[i] = (i == 0) ? BS_ : 0;
    if (i == 0) {
        const u16* w = (const u16*)x;
        int sane = 0;
        for (int t = 0; t < 256; ++t) {
            int e = (w[2 * t] >> 7) & 0xFF;
            if (e >= 100 && e <= 135) ++sane;
        }
        *flag = (sane >= 192) ? 1 : 0;   // 1 = bf16, 0 = fp32
    }
}

// ---------------- prepack W into MFMA fragment layout ----------------
// wpk[((z*32 + ks)*16 + 2*t + plane)*64 + lane] : u32x4
//   lane = 16*q + c holds plane (0=hi,1=lo) f16x8 of W[16*t + c][ks*32 + 8*q .. +8)
// grid: 192 x 256   (3 * 32 * 8 * 64 = 49152 fragments-pairs)
__global__ __launch_bounds__(256) void prepack_w_kernel(
    const void* __restrict__ wq, const void* __restrict__ wk, const void* __restrict__ wv,
    const int* __restrict__ flag, u32x4* __restrict__ wpk)
{
    const int isb = *flag;
    const int gid = blockIdx.x * 256 + threadIdx.x;
    const int l  = gid & 63;
    const int t  = (gid >> 6) & 7;
    const int ks = (gid >> 9) & 31;
    const int z  = gid >> 14;
    const void* W = (z == 0) ? wq : (z == 1) ? wk : wv;
    const int row = 16 * t + (l & 15);
    const int k0  = ks * 32 + 8 * (l >> 4);
    float f[8];
    ld8(W, (size_t)row * DM + k0, isb, f);
    u32x4 hi, lo;
    split8(f, hi, lo);
    const size_t base = ((((size_t)z * 32 + ks) * 16) + 2 * t) * 64 + l;
    wpk[base]      = hi;
    wpk[base + 64] = lo;
}

// ---------------- MFMA QKV v3: prepacked W + global_load_lds staging ----------------
__global__ __launch_bounds__(256) void qkv_kernel(
    const void* __restrict__ x, const u32x4* __restrict__ wpk,
    const int* __restrict__ flag, u32* __restrict__ qkv)
{
    const int isb = *flag;
    const int z = blockIdx.z;
    u32* out = qkv + (size_t)z * ((size_t)BS_ * DH);
    const int m0 = blockIdx.x * 64;
    const int tid = threadIdx.x;
    const int wave = tid >> 6, lane = tid & 63;
    const int qd = lane >> 4, c = lane & 15;

    __shared__ u32x4 WL[2][8][2][64];   // [buf][colTile][hi/lo][lane] 32 KB

    const u32x4* wz = wpk + (size_t)z * (32 * 16 * 64);
    const size_t arow = (size_t)(m0 + wave * 16 + c) * DM + 8 * qd;

    // stage K-step ks's 16 slabs (8 tiles x hi/lo) into buffer b.
    // wave w handles slabs 4w..4w+3; each slab = 64 lanes x 16B, linear both sides.
#define STAGE_W(ks_, b_)                                                          \
    {                                                                             \
        const u32x4* _src = wz + ((size_t)(ks_) * 16 + 4 * wave) * 64 + lane;     \
        _Pragma("unroll")                                                         \
        for (int _j = 0; _j < 4; ++_j) {                                          \
            __builtin_amdgcn_global_load_lds(                                     \
                (const __attribute__((address_space(1))) u32*)(_src + _j * 64),   \
                (__attribute__((address_space(3))) u32*)&WL[b_][2 * wave + (_j >> 1)][_j & 1][0], \
                16, 0, 0);                                                        \
        }                                                                         \
    }

    float Ar[8], Arn[8];
    ld8(x, arow, isb, Ar);
    STAGE_W(0, 0);
    ld8(x, arow + 32, isb, Arn);
    __syncthreads();

    f32x4 acc[8] = {};

    for (int ks = 0; ks < 32; ++ks) {
        const int cb = ks & 1;
        // issue next tile's staging first: loads fly under the MFMAs,
        // drained by the (compiler-emitted) vmcnt(0) before the barrier below.
        if (ks + 1 < 32) STAGE_W(ks + 1, cb ^ 1);

        H8 Ah, Al;
        split8(Ar, Ah.v, Al.v);
#pragma unroll
        for (int t = 0; t < 8; ++t) {
            H8 bh, bl;
            bh.v = WL[cb][t][0][lane]; bl.v = WL[cb][t][1][lane];
            acc[t] = __builtin_amdgcn_mfma_f32_16x16x32_f16(Al.h, bh.h, acc[t], 0, 0, 0);
            acc[t] = __builtin_amdgcn_mfma_f32_16x16x32_f16(Ah.h, bl.h, acc[t], 0, 0, 0);
            acc[t] = __builtin_amdgcn_mfma_f32_16x16x32_f16(Ah.h, bh.h, acc[t], 0, 0, 0);
        }
#pragma unroll
        for (int j = 0; j < 8; ++j) Ar[j] = Arn[j];
        if (ks + 2 < 32) ld8(x, arow + (size_t)(ks + 2) * 32, isb, Arn);
        __syncthreads();
    }
#undef STAGE_W

#pragma unroll
    for (int r = 0; r < 4; ++r) {
        const int row = m0 + wave * 16 + qd * 4 + r;
        u32* op = out + (size_t)row * DH + c;
#pragma unroll
        for (int t = 0; t < 8; ++t) op[t * 16] = f2pk(acc[t][r]);
    }
}

// ---------------- attention core (shared by both variants) ----------------
// Computes UNNORMALIZED O (f32x4[8]) and per-lane lsum[4] over KV tiles
// [kt0, kt1). Q frags from qp. One barrier per tile (dbuf).
template <bool WRITE_PARTIAL>
__device__ __forceinline__ void attn_body(
    const u32* qp, const u32* __restrict__ kp, const u32* __restrict__ vp,
    float* outO, float* outL, float* cur,
    int b, int q0, int kt0, int kt1, int part)
{
    const int tid = threadIdx.x;
    const int wave = tid >> 6, lane = tid & 63;
    const int qd = lane >> 4, c = lane & 15;

    __shared__ u32x4 KF[2][2][2][4][64];  // [buf][plane][tile][ks][lane] 32 KB
    __shared__ u32x4 VF[2][2][8][64];     // [buf][plane][t][lane]       32 KB
    __shared__ u32   PB[4][531];          // per-wave P, elem-packed, stride 33

    H8 Qh[4], Ql[4];
    {
        const u32* qr = qp + ((size_t)b * S_ + q0 + wave * 16 + c) * DH;
#pragma unroll
        for (int ks = 0; ks < 4; ++ks) {
            uint4 e0 = *(const uint4*)(qr + ks * 32 + qd * 8);
            uint4 e1 = *(const uint4*)(qr + ks * 32 + qd * 8 + 4);
            Qh[ks].u[0] = permHI(e0.y, e0.x); Qh[ks].u[1] = permHI(e0.w, e0.z);
            Qh[ks].u[2] = permHI(e1.y, e1.x); Qh[ks].u[3] = permHI(e1.w, e1.z);
            Ql[ks].u[0] = permLO(e0.y, e0.x); Ql[ks].u[1] = permLO(e0.w, e0.z);
            Ql[ks].u[2] = permLO(e1.y, e1.x); Ql[ks].u[3] = permLO(e1.w, e1.z);
        }
    }

    const int kKey = tid & 31, kD0 = (tid >> 5) * 16;
    const int vD = tid >> 1, vKg = (tid & 1) * 16;
    const int tK = (tid >> 4) & 1, cK = tid & 15;
    const int tV = tid >> 5,      cV = (tid >> 1) & 15;

    uint4 Kst[4]; u32 Vst[16];

    auto loadKV = [&](int kb) {
        const u32* kr = kp + ((size_t)b * S_ + kb * 32 + kKey) * DH + kD0;
#pragma unroll
        for (int j = 0; j < 4; ++j) Kst[j] = *(const uint4*)(kr + 4 * j);
        const u32* vc = vp + ((size_t)b * S_ + kb * 32 + vKg) * DH + vD;
#pragma unroll
        for (int j = 0; j < 16; ++j) Vst[j] = vc[(size_t)j * DH];
    };
    auto writeKV = [&](int wb) {
#pragma unroll
        for (int g = 0; g < 2; ++g) {
            const int dg = kD0 + 8 * g, ksK = dg >> 5, qK = (dg >> 3) & 3;
            KF[wb][0][tK][ksK][qK * 16 + cK] = (u32x4){
                permHI(Kst[2*g].y, Kst[2*g].x), permHI(Kst[2*g].w, Kst[2*g].z),
                permHI(Kst[2*g+1].y, Kst[2*g+1].x), permHI(Kst[2*g+1].w, Kst[2*g+1].z)};
            KF[wb][1][tK][ksK][qK * 16 + cK] = (u32x4){
                permLO(Kst[2*g].y, Kst[2*g].x), permLO(Kst[2*g].w, Kst[2*g].z),
                permLO(Kst[2*g+1].y, Kst[2*g+1].x), permLO(Kst[2*g+1].w, Kst[2*g+1].z)};
        }
#pragma unroll
        for (int g = 0; g < 2; ++g) {
            const int qV = 2 * (tid & 1) + g;
            VF[wb][0][tV][qV * 16 + cV] = (u32x4){
                permHI(Vst[8*g+1], Vst[8*g+0]), permHI(Vst[8*g+3], Vst[8*g+2]),
                permHI(Vst[8*g+5], Vst[8*g+4]), permHI(Vst[8*g+7], Vst[8*g+6])};
            VF[wb][1][tV][qV * 16 + cV] = (u32x4){
                permLO(Vst[8*g+1], Vst[8*g+0]), permLO(Vst[8*g+3], Vst[8*g+2]),
                permLO(Vst[8*g+5], Vst[8*g+4]), permLO(Vst[8*g+7], Vst[8*g+6])};
        }
    };

    loadKV(kt0);
    writeKV(0);
    if (kt0 + 1 < kt1) loadKV(kt0 + 1);
    __syncthreads();

    f32x4 O[8] = {};
    float lsum[4] = {};

    for (int kt = kt0; kt < kt1; ++kt) {
        const int cb = (kt - kt0) & 1;

        f32x4 S0 = {}, S1 = {};
#pragma unroll
        for (int ks = 0; ks < 4; ++ks) {
            H8 kh, kl;
            kh.v = KF[cb][0][0][ks][lane]; kl.v = KF[cb][1][0][ks][lane];
            S0 = __builtin_amdgcn_mfma_f32_16x16x32_f16(Ql[ks].h, kh.h, S0, 0, 0, 0);
            S0 = __builtin_amdgcn_mfma_f32_16x16x32_f16(Qh[ks].h, kl.h, S0, 0, 0, 0);
            S0 = __builtin_amdgcn_mfma_f32_16x16x32_f16(Qh[ks].h, kh.h, S0, 0, 0, 0);
            kh.v = KF[cb][0][1][ks][lane]; kl.v = KF[cb][1][1][ks][lane];
            S1 = __builtin_amdgcn_mfma_f32_16x16x32_f16(Ql[ks].h, kh.h, S1, 0, 0, 0);
            S1 = __builtin_amdgcn_mfma_f32_16x16x32_f16(Qh[ks].h, kl.h, S1, 0, 0, 0);
            S1 = __builtin_amdgcn_mfma_f32_16x16x32_f16(Qh[ks].h, kh.h, S1, 0, 0, 0);
        }

        u32* pw = PB[wave];
#pragma unroll
        for (int r = 0; r < 4; ++r) {
            float e0 = exp2f(fmaf(S0[r], SCALE2_, -4.0f));
            float e1 = exp2f(fmaf(S1[r], SCALE2_, -4.0f));
            lsum[r] += e0 + e1;
            pw[(4 * qd + r) * 33 + c]      = f2pk(e0);
            pw[(4 * qd + r) * 33 + 16 + c] = f2pk(e1);
        }

        u32 e[8];
#pragma unroll
        for (int j = 0; j < 8; ++j) e[j] = pw[c * 33 + 8 * qd + j];
        H8 Ph, Pl;
        Ph.u[0] = permHI(e[1], e[0]); Ph.u[1] = permHI(e[3], e[2]);
        Ph.u[2] = permHI(e[5], e[4]); Ph.u[3] = permHI(e[7], e[6]);
        Pl.u[0] = permLO(e[1], e[0]); Pl.u[1] = permLO(e[3], e[2]);
        Pl.u[2] = permLO(e[5], e[4]); Pl.u[3] = permLO(e[7], e[6]);

#pragma unroll
        for (int t = 0; t < 8; ++t) {
            H8 vh, vl;
            vh.v = VF[cb][0][t][lane]; vl.v = VF[cb][1][t][lane];
            O[t] = __builtin_amdgcn_mfma_f32_16x16x32_f16(Pl.h, vh.h, O[t], 0, 0, 0);
            O[t] = __builtin_amdgcn_mfma_f32_16x16x32_f16(Ph.h, vl.h, O[t], 0, 0, 0);
            O[t] = __builtin_amdgcn_mfma_f32_16x16x32_f16(Ph.h, vh.h, O[t], 0, 0, 0);
        }

        if (kt + 1 < kt1) {
            writeKV((kt + 1 - kt0) & 1);
            if (kt + 2 < kt1) loadKV(kt + 2);
        }
        __syncthreads();
    }

    if (WRITE_PARTIAL) {
        // unnormalized O + per-row l to partial buffers
        float lred[4];
#pragma unroll
        for (int r = 0; r < 4; ++r) {
            float l = lsum[r];
            l += __shfl_xor(l, 1); l += __shfl_xor(l, 2);
            l += __shfl_xor(l, 4); l += __shfl_xor(l, 8);
            lred[r] = l;
        }
        const size_t rb = (size_t)b * S_ + q0 + wave * 16 + 4 * qd;
        float* Op = outO + (size_t)part * ((size_t)BS_ * DH);
#pragma unroll
        for (int t = 0; t < 8; ++t)
#pragma unroll
            for (int r = 0; r < 4; ++r)
                Op[(rb + r) * DH + t * 16 + c] = O[t][r];
        if (c == 0) {
            float* lp = outL + (size_t)part * BS_;
#pragma unroll
            for (int r = 0; r < 4; ++r) lp[rb + r] = lred[r];
        }
    } else {
        float linv[4];
#pragma unroll
        for (int r = 0; r < 4; ++r) {
            float l = lsum[r];
            l += __shfl_xor(l, 1); l += __shfl_xor(l, 2);
            l += __shfl_xor(l, 4); l += __shfl_xor(l, 8);
            linv[r] = 1.0f / l;
        }
        const size_t rb = (size_t)b * S_ + q0 + wave * 16 + 4 * qd;
#pragma unroll
        for (int t = 0; t < 8; ++t)
#pragma unroll
            for (int r = 0; r < 4; ++r)
                cur[(rb + r) * DH + t * 16 + c] = O[t][r] * linv[r];
    }
}

// single-pass fallback (small ws): grid (S/64, B)
__global__ __launch_bounds__(256) void attn_kernel(
    const u32* qp, const u32* __restrict__ kp, const u32* __restrict__ vp, float* cur)
{
    attn_body<false>(qp, kp, vp, nullptr, nullptr, cur,
                     blockIdx.y, blockIdx.x * 64, 0, S_ / 32, 0);
}

// split-KV x2: grid (S/64, B, 2) = 512 blocks (2 blocks/CU)
__global__ __launch_bounds__(256) void attn_split_kernel(
    const u32* qp, const u32* __restrict__ kp, const u32* __restrict__ vp,
    float* __restrict__ Opart, float* __restrict__ lpart)
{
    const int part = blockIdx.z;
    const int half = S_ / 64;   // 32 tiles per part
    attn_body<true>(qp, kp, vp, Opart, lpart, nullptr,
                    blockIdx.y, blockIdx.x * 64, part * half, (part + 1) * half, part);
}

// combine: cur0 = (Oa + Ob) / (la + lb). grid 512 x 256, 16 elems/thread.
__global__ __launch_bounds__(256) void combine_kernel(
    const float* __restrict__ Opart, const float* __restrict__ lpart,
    float* __restrict__ cur)
{
    const size_t N1 = (size_t)BS_ * DH;
    const size_t i0 = ((size_t)blockIdx.x * 256 + threadIdx.x) * 16;
    const int row = (int)(i0 >> 7);
    const float linv = 1.0f / (lpart[row] + lpart[BS_ + row]);
#pragma unroll
    for (int t = 0; t < 4; ++t) {
        float4 a = *(const float4*)(Opart + i0 + t * 4);
        float4 b = *(const float4*)(Opart + N1 + i0 + t * 4);
        *(float4*)(cur + i0 + t * 4) = make_float4(
            (a.x + b.x) * linv, (a.y + b.y) * linv,
            (a.z + b.z) * linv, (a.w + b.w) * linv);
    }
}

// ---------------- one dialectic round: 64 tokens/block ----------------
__global__ __launch_bounds__(256) void round_kernel(
    const float* cur0, const float* curr,
    const void* __restrict__ tw, const void* __restrict__ tb, const void* __restrict__ ab,
    const void* __restrict__ w1, const void* __restrict__ b1,
    const void* __restrict__ w2, const void* __restrict__ b2,
    const void* __restrict__ gw, const void* __restrict__ gb,
    const int* __restrict__ flag, int* active, int* counts, int r,
    float* cur_out, void* dout)
{
    const int isb = *flag;
    const int tok0 = blockIdx.x * 64;
    const int tid = threadIdx.x;
    const bool last = (dout != nullptr);

    if (counts[r] <= 0) {
        if (last) {
            for (int e = tid; e < 64 * DH; e += 256) {
                size_t idx = (size_t)tok0 * DH + e;
                float v = curr[idx];
                if (isb) ((__hip_bfloat16*)dout)[idx] = __float2bfloat16(v);
                else     ((float*)dout)[idx] = v;
            }
        }
        return;
    }

    __shared__ float As[32][65];
    __shared__ float Ws[32][129];
    __shared__ float HS[128 * 65];
    __shared__ float actS[64], tbS[128], abS[128], b1S[128], b2S[128], gwS[256];
    __shared__ int blkcnt;

    if (tid < 64) actS[tid] = active[tok0 + tid] ? 1.0f : 0.0f;
    if (tid < 128) {
        tbS[tid] = ldE(tb, tid, isb); abS[tid] = ldE(ab, tid, isb);
        b1S[tid] = ldE(b1, tid, isb); b2S[tid] = ldE(b2, tid, isb);
    }
    gwS[tid] = ldE(gw, tid, isb);
    if (tid == 0) blkcnt = 0;
    const float gbf = ldE(gb, 0, isb);
    __syncthreads();

    const int tm = (tid & 15) * 4, tn = (tid >> 4) * 8;
    const int ar = tid >> 2, ac4 = (tid & 3) * 8;
    const int bn = tid >> 1, bc = (tid & 1) * 16;

    // ---- t0 = cur0_tile @ tw^T ----
    {
        float acc[4][8] = {};
        for (int s = 0; s < 4; ++s) {
            const int k0 = s * 32;
            float4 a0 = *(const float4*)(cur0 + (size_t)(tok0 + ar) * DH + k0 + ac4);
            float4 a1 = *(const float4*)(cur0 + (size_t)(tok0 + ar) * DH + k0 + ac4 + 4);
            float bf0[8], bf1[8];
            ld8(tw, (size_t)bn * DH + k0 + bc, isb, bf0);
            ld8(tw, (size_t)bn * DH + k0 + bc + 8, isb, bf1);
            __syncthreads();
            As[ac4 + 0][ar] = a0.x; As[ac4 + 1][ar] = a0.y; As[ac4 + 2][ar] = a0.z; As[ac4 + 3][ar] = a0.w;
            As[ac4 + 4][ar] = a1.x; As[ac4 + 5][ar] = a1.y; As[ac4 + 6][ar] = a1.z; As[ac4 + 7][ar] = a1.w;
#pragma unroll
            for (int j = 0; j < 8; ++j) { Ws[bc + j][bn] = bf0[j]; Ws[bc + 8 + j][bn] = bf1[j]; }
            __syncthreads();
#pragma unroll 8
            for (int kk = 0; kk < 32; ++kk) {
                float a0v = As[kk][tm], a1v = As[kk][tm + 1], a2v = As[kk][tm + 2], a3v = As[kk][tm + 3];
#pragma unroll
                for (int j = 0; j < 8; ++j) {
                    float bb = Ws[kk][tn + j];
                    acc[0][j] += a0v * bb; acc[1][j] += a1v * bb;
                    acc[2][j] += a2v * bb; acc[3][j] += a3v * bb;
                }
            }
        }
#pragma unroll
        for (int i = 0; i < 4; ++i)
#pragma unroll
            for (int j = 0; j < 8; ++j)
                HS[(tm + i) * 129 + (tn + j)] = acc[i][j];
        __syncthreads();
    }

    // ---- layer 1: h = relu([at,aa,ac] @ w1^T + b1) ----
    float acc1[4][8] = {};
    for (int s = 0; s < 12; ++s) {
        const int k0 = s * 32;
        const int col0 = (s & 3) * 32;
        const float am = actS[ar];
        float av[8];
        if (s < 4) {
#pragma unroll
            for (int j = 0; j < 8; ++j) {
                int cc = col0 + ac4 + j;
                av[j] = (HS[ar * 129 + cc] + tbS[cc]) * am;
            }
        } else if (s < 8) {
#pragma unroll
            for (int j = 0; j < 8; ++j) {
                int cc = col0 + ac4 + j;
                av[j] = (abS[cc] - HS[ar * 129 + cc]) * am;
            }
        } else {
            float4 a0 = *(const float4*)(curr + (size_t)(tok0 + ar) * DH + col0 + ac4);
            float4 a1 = *(const float4*)(curr + (size_t)(tok0 + ar) * DH + col0 + ac4 + 4);
            av[0] = a0.x * am; av[1] = a0.y * am; av[2] = a0.z * am; av[3] = a0.w * am;
            av[4] = a1.x * am; av[5] = a1.y * am; av[6] = a1.z * am; av[7] = a1.w * am;
        }
        float bf0[8], bf1[8];
        ld8(w1, (size_t)bn * 384 + k0 + bc, isb, bf0);
        ld8(w1, (size_t)bn * 384 + k0 + bc + 8, isb, bf1);
        __syncthreads();
#pragma unroll
        for (int j = 0; j < 8; ++j) As[ac4 + j][ar] = av[j];
#pragma unroll
        for (int j = 0; j < 8; ++j) { Ws[bc + j][bn] = bf0[j]; Ws[bc + 8 + j][bn] = bf1[j]; }
        __syncthreads();
#pragma unroll 8
        for (int kk = 0; kk < 32; ++kk) {
            float a0v = As[kk][tm], a1v = As[kk][tm + 1], a2v = As[kk][tm + 2], a3v = As[kk][tm + 3];
#pragma unroll
            for (int j = 0; j < 8; ++j) {
                float bb = Ws[kk][tn + j];
                acc1[0][j] += a0v * bb; acc1[1][j] += a1v * bb;
                acc1[2][j] += a2v * bb; acc1[3][j] += a3v * bb;
            }
        }
    }
#pragma unroll
    for (int i = 0; i < 4; ++i)
#pragma unroll
        for (int j = 0; j < 8; ++j)
            HS[(tn + j) * 65 + (tm + i)] = fmaxf(acc1[i][j] + b1S[tn + j], 0.0f);

    // ---- layer 2 ----
    float acc2[4][8] = {};
    for (int s = 0; s < 4; ++s) {
        const int k0 = s * 32;
        float bf0[8], bf1[8];
        ld8(w2, (size_t)bn * DH + k0 + bc, isb, bf0);
        ld8(w2, (size_t)bn * DH + k0 + bc + 8, isb, bf1);
        __syncthreads();
#pragma unroll
        for (int j = 0; j < 8; ++j) { Ws[bc + j][bn] = bf0[j]; Ws[bc + 8 + j][bn] = bf1[j]; }
        __syncthreads();
#pragma unroll 8
        for (int kk = 0; kk < 32; ++kk) {
            float a0v = HS[(k0 + kk) * 65 + tm];
            float a1v = HS[(k0 + kk) * 65 + tm + 1];
            float a2v = HS[(k0 + kk) * 65 + tm + 2];
            float a3v = HS[(k0 + kk) * 65 + tm + 3];
#pragma unroll
            for (int j = 0; j < 8; ++j) {
                float bb = Ws[kk][tn + j];
                acc2[0][j] += a0v * bb; acc2[1][j] += a1v * bb;
                acc2[2][j] += a2v * bb; acc2[3][j] += a3v * bb;
            }
        }
    }
    __syncthreads();
#pragma unroll
    for (int i = 0; i < 4; ++i)
#pragma unroll
        for (int j = 0; j < 8; ++j)
            HS[(tm + i) * 129 + (tn + j)] = acc2[i][j] + b2S[tn + j];
    __syncthreads();

    // ---- gate, update, norm, active ----
    const int tok = tid >> 2, d0 = (tid & 3) * 32;
    const float am = actS[tok];
    const float* cp = curr + (size_t)(tok0 + tok) * DH + d0;
    float cv[32];
#pragma unroll
    for (int t = 0; t < 8; ++t) {
        float4 vv = *(const float4*)(cp + t * 4);
        cv[t * 4] = vv.x; cv[t * 4 + 1] = vv.y; cv[t * 4 + 2] = vv.z; cv[t * 4 + 3] = vv.w;
    }
    const float* srow = HS + tok * 129 + d0;
    float gp = 0.0f;
#pragma unroll
    for (int e = 0; e < 32; ++e)
        gp += cv[e] * am * gwS[d0 + e] + srow[e] * gwS[128 + d0 + e];
    gp += __shfl_xor(gp, 1, 4);
    gp += __shfl_xor(gp, 2, 4);
    const float gate = 1.0f / (1.0f + __expf(-(gp + gbf)));
    float ss = 0.0f; float up[32];
#pragma unroll
    for (int e = 0; e < 32; ++e) {
        float u = gate * (srow[e] - cv[e] * am) * 0.1f;
        up[e] = u; ss += u * u;
    }
    ss += __shfl_xor(ss, 1, 4);
    ss += __shfl_xor(ss, 2, 4);
    const bool stable = sqrtf(ss) < 0.1f;

    if (last) {
        size_t off = (size_t)(tok0 + tok) * DH + d0;
        if (isb) {
            __hip_bfloat16* op = (__hip_bfloat16*)dout + off;
#pragma unroll
            for (int e = 0; e < 32; ++e) op[e] = __float2bfloat16(cv[e] + up[e]);
        } else {
            float* op = (float*)dout + off;
#pragma unroll
            for (int t = 0; t < 8; ++t)
                *(float4*)(op + t * 4) = make_float4(cv[t * 4] + up[t * 4], cv[t * 4 + 1] + up[t * 4 + 1],
                                                     cv[t * 4 + 2] + up[t * 4 + 2], cv[t * 4 + 3] + up[t * 4 + 3]);
        }
    } else {
        float* op = cur_out + (size_t)(tok0 + tok) * DH + d0;
#pragma unroll
        for (int t = 0; t < 8; ++t)
            *(float4*)(op + t * 4) = make_float4(cv[t * 4] + up[t * 4], cv[t * 4 + 1] + up[t * 4 + 1],
                                                 cv[t * 4 + 2] + up[t * 4 + 2], cv[t * 4 + 3] + up[t * 4 + 3]);
    }
    const int newact = (am > 0.0f && !stable) ? 1 : 0;
    if ((tid & 3) == 0) {
        active[tok0 + tok] = newact;
        if (newact) atomicAdd(&blkcnt, 1);
    }
    __syncthreads();
    if (tid == 0 && blkcnt > 0) atomicAdd(&counts[r + 1], blkcnt);
}

extern "C" void kernel_launch(void* const* d_in, const int* in_sizes, int n_in,
                              void* d_out, int out_size, void* d_ws, size_t ws_size,
                              hipStream_t stream) {
    const void* x  = d_in[0];
    const void* wq = d_in[1];
    const void* wk = d_in[2];
    const void* wv = d_in[3];
    const void* tw = d_in[4];
    const void* tb = d_in[5];
    const void* ab = d_in[6];
    const void* w1 = d_in[7];
    const void* b1 = d_in[8];
    const void* w2 = d_in[9];
    const void* b2 = d_in[10];
    const void* gw = d_in[11];
    const void* gb = d_in[12];

    u32* ws = (u32*)d_ws;
    const size_t N1 = (size_t)BS_ * DH;
    // base layout (~24 MiB): qp | kp | vp | active | counts | flag
    u32* qp = ws;
    u32* kp = ws + N1;
    u32* vp = ws + 2 * N1;
    int* active = (int*)(ws + 3 * N1);
    int* counts = active + BS_;
    int* flag   = counts + 4;
    float* cur0  = (float*)qp;
    float* cur_r = (float*)kp;
    // split-KV extension (needs ~42.3 MB total):
    float* Opart = (float*)(ws + 3 * N1 + 32768);           // 2 x N1 fp32
    float* lpart = (float*)(ws + 5 * N1 + 32768);           // 2 x BS_ fp32
    const bool big_ws = ws_size >= (size_t)42300000;        // constant across calls
    // prepacked W lives in the Opart region: only needed before attention
    // writes Opart (3*32*16*64 u32x4 = 1.5 MB << 16.8 MB region). 16B aligned.
    u32x4* wpk = (u32x4*)(ws + 3 * N1 + 32768);

    init_kernel<<<dim3(BS_ / 256), 256, 0, stream>>>(x, flag, active, counts);
    prepack_w_kernel<<<dim3(192), 256, 0, stream>>>(wq, wk, wv, flag, wpk);
    qkv_kernel<<<dim3(BS_ / 64, 1, 3), 256, 0, stream>>>(x, wpk, flag, qp);
    if (big_ws) {
        attn_split_kernel<<<dim3(S_ / 64, B_, 2), 256, 0, stream>>>(qp, kp, vp, Opart, lpart);
        combine_kernel<<<dim3(512), 256, 0, stream>>>(Opart, lpart, cur0);
    } else {
        attn_kernel<<<dim3(S_ / 64, B_), 256, 0, stream>>>(qp, kp, vp, cur0);
    }
    round_kernel<<<dim3(BS_ / 64), 256, 0, stream>>>(
        cur0, cur0, tw, tb, ab, w1, b1, w2, b2, gw, gb, flag, active, counts, 0, cur_r, nullptr);
    round_kernel<<<dim3(BS_ / 64), 256, 0, stream>>>(
        cur0, cur_r, tw, tb, ab, w1, b1, w2, b2, gw, gb, flag, active, counts, 1, cur_r, nullptr);
    round_kernel<<<dim3(BS_ / 64), 256, 0, stream>>>(
        cur0, cur_r, tw, tb, ab, w1, b1, w2, b2, gw, gb, flag, active, counts, 2, cur_r, d_out);
}